// Round 7
// baseline (284.722 us; speedup 1.0000x reference)
//
#include <hip/hip_runtime.h>

// N=4096, A=512, C=100 (derived at launch).
// Outputs flat: [loss(1), new_cov(C*A*A), new_ave(C*A), new_amount(C)]
//
// ONE dispatch. Grid (NPAIRS, 1, LZ+AZ+C) where NPAIRS = T*(T+1)/2, T=A/TM:
//   z in [0,LZ)      : CE-loss rider blocks.
//   z in [LZ,LZ+AZ)  : new_ave rider blocks (one class per block; also new_amount).
//   z >= LZ+AZ       : cov tile-pair blocks, class c = z-LZ-AZ, blockIdx.x ->
//                      upper-triangle pair (ai<=bi). SYMMETRY: C[a][b]==C[b][a]
//                      bit-identically (same fp32 sum), so only 10 of 16 tiles
//                      are computed; off-diagonal tiles are mirrored via an LDS
//                      transpose + coalesced stores. Diagonal tiles stage only
//                      Xa (B-side aliases it): half the gather + LDS stores.
// Cov tile: RAW outer products (E[xx^T]-mu mu^T identity), REGISTER-staged
// float4 gather (round-2 DMA staging amplified HBM 4x — keep feats L2-resident),
// LDS double-buffer -> ONE barrier per k-chunk, PACKED v_pk_fma_f32 inner loop,
// per-thread scalar column sums, label-scan member lists (no prep kernel),
// nontemporal streaming stores. cov_in folded at EPILOGUE (handles asymmetric
// cov_in under mirroring); skipped when w==1 (always true for Amount=0 inputs).
//
// NOTE: plain __launch_bounds__(256). A (256,4) bound capped VGPR at 64 and
// spilled the 64-float accumulator to scratch (+395 MB HBM traffic, 2x dur).
// out_loss zero-init via hipMemsetAsync (stream-ordered, graph-capturable).

#define TM 128
#define KC 16      // members per k-chunk
#define LSTR 132   // padded LDS row stride (floats)
#define LZ 8       // loss z-slices

typedef float nf4 __attribute__((ext_vector_type(4)));   // nontemporal vector
typedef float f2  __attribute__((ext_vector_type(2)));   // packed-FMA pair

// ---------------- mega: loss riders + ave riders + cov ----------------
__global__ __launch_bounds__(256) void mega_kernel(
    const float* __restrict__ feats, const float* __restrict__ cov_in,
    const float* __restrict__ Ave_in, const float* __restrict__ y_s,
    const int* __restrict__ labels, const float* __restrict__ Amount,
    float* __restrict__ out_cov, float* __restrict__ out_ave,
    float* __restrict__ out_amt, float* __restrict__ out_loss0,
    int N, int C, int A, float invN, int AZ) {

    const int nxy = gridDim.x * gridDim.y;
    const int bxy = blockIdx.y * gridDim.x + blockIdx.x;
    const int tid = threadIdx.x;

    // ---- loss rider blocks (z in [0, LZ)) ----
    if ((int)blockIdx.z < LZ) {
        __shared__ float bsum[4];
        const int lane = tid & 63;
        const int wv = tid >> 6;
        const int bid = (int)blockIdx.z * nxy + bxy;
        const int nwaves = LZ * nxy * 4;
        const int gw = bid * 4 + wv;
        float wsum = 0.f;
        for (int r = gw; r < N; r += nwaves) {
            const float* row = y_s + (size_t)r * C;
            float m = -1e30f;
            for (int col = lane; col < C; col += 64) m = fmaxf(m, row[col]);
            #pragma unroll
            for (int off = 32; off > 0; off >>= 1) m = fmaxf(m, __shfl_xor(m, off));
            float se = 0.f;
            for (int col = lane; col < C; col += 64) se += __expf(row[col] - m);
            #pragma unroll
            for (int off = 32; off > 0; off >>= 1) se += __shfl_xor(se, off);
            if (lane == 0) wsum += -(row[labels[r]] - m - __logf(se));
        }
        if (lane == 0) bsum[wv] = wsum;
        __syncthreads();
        if (tid == 0)
            atomicAdd(out_loss0, (bsum[0] + bsum[1] + bsum[2] + bsum[3]) * invN);
        return;
    }

    // ---- ave rider blocks (z in [LZ, LZ+AZ)): one class per block ----
    if ((int)blockIdx.z < LZ + AZ) {
        __shared__ int idxs[256];
        __shared__ int acnt;
        const int bid = ((int)blockIdx.z - LZ) * nxy + bxy;
        if (bid >= C) return;
        const int c = bid;
        if (tid == 0) acnt = 0;
        __syncthreads();
        for (int i = tid; i < N; i += 256)
            if (labels[i] == c) { int p = atomicAdd(&acnt, 1); if (p < 256) idxs[p] = i; }
        __syncthreads();
        const int nc = min(acnt, 256);
        const float cf = (float)nc;
        const float ic = 1.f / fmaxf(cf, 1.f);
        const float am = Amount[c];
        const float dn = cf + am;
        const float w = dn > 0.f ? cf / dn : 0.f;
        if (tid == 0) out_amt[c] = am + cf;
        for (int c0 = 0; c0 < A; c0 += 512) {
            const int colA = c0 + tid;
            const int colB = c0 + 256 + tid;
            float s0 = 0.f, s1 = 0.f;
            int j = 0;
            for (; j + 3 < nc; j += 4) {
                const float* f0 = feats + (size_t)idxs[j] * A;
                const float* f1 = feats + (size_t)idxs[j + 1] * A;
                const float* f2p = feats + (size_t)idxs[j + 2] * A;
                const float* f3 = feats + (size_t)idxs[j + 3] * A;
                if (colA < A) s0 += f0[colA] + f1[colA] + f2p[colA] + f3[colA];
                if (colB < A) s1 += f0[colB] + f1[colB] + f2p[colB] + f3[colB];
            }
            for (; j < nc; ++j) {
                const float* fr = feats + (size_t)idxs[j] * A;
                if (colA < A) s0 += fr[colA];
                if (colB < A) s1 += fr[colB];
            }
            if (colA < A)
                out_ave[(size_t)c * A + colA] =
                    Ave_in[(size_t)c * A + colA] * (1.f - w) + (s0 * ic) * w;
            if (colB < A)
                out_ave[(size_t)c * A + colB] =
                    Ave_in[(size_t)c * A + colB] * (1.f - w) + (s1 * ic) * w;
        }
        return;
    }

    // ---- cov tile-pair: class c, upper-triangle pair (ai<=bi) ----
    const int c  = (int)blockIdx.z - LZ - AZ;
    // map blockIdx.x -> (ai,bi), ai<=bi, row-major upper triangle
    int ai = 0, rem = (int)blockIdx.x, span = A / TM;
    while (rem >= span) { rem -= span; ++ai; --span; }
    const int bi = ai + rem;
    const bool diag = (ai == bi);
    const int a0 = ai * TM;
    const int b0 = bi * TM;

    // [buf][0=A-tile,1=B-tile][k][col], padded stride
    __shared__ float Xs[2][2][KC][LSTR];
    __shared__ float muA[TM], muB[TM], dA[TM], dB[TM];
    __shared__ int idxbuf[256];
    __shared__ int ccnt;

    const int ty = tid >> 4, tx = tid & 15;
    const int ty4 = ty * 4, tx4 = tx * 4;

    // scan labels -> member list for class c (L2-resident 16KB)
    if (tid == 0) ccnt = 0;
    __syncthreads();
    for (int i = tid; i < N; i += 256)
        if (labels[i] == c) { int p = atomicAdd(&ccnt, 1); if (p < 256) idxbuf[p] = i; }
    __syncthreads();
    const int nc = min(ccnt, 256);

    const float cf  = (float)nc;
    const float ic  = 1.f / fmaxf(cf, 1.f);
    const float am  = Amount[c];
    const float dn  = cf + am;
    const float w   = dn > 0.f ? cf / dn : 0.f;
    const float omw = 1.f - w;
    const float s   = ic * w;
    const float aw  = w * omw;
    const size_t cbase = (size_t)c * A * A;

    if (s > 0.f) {
        const int nchunks = (nc + KC - 1) / KC;
        const int li = ty;            // staging member row (0..15)
        const int cg = tx4;           // staging col group

        float4 v0, v1, v2, v3;        // pipeline registers (RAW values)
        auto LOADV = [&](int ch) {
            const int slot = ch * KC + li;
            v0 = make_float4(0.f, 0.f, 0.f, 0.f); v1 = v0; v2 = v0; v3 = v0;
            if (slot < nc) {
                int row = idxbuf[slot];
                const float* fr = feats + (size_t)row * A;
                v0 = *reinterpret_cast<const float4*>(fr + a0 + cg);
                v1 = *reinterpret_cast<const float4*>(fr + a0 + cg + 64);
                if (!diag) {
                    v2 = *reinterpret_cast<const float4*>(fr + b0 + cg);
                    v3 = *reinterpret_cast<const float4*>(fr + b0 + cg + 64);
                }
            }
        };
        auto STORE_LDS = [&](int b) {
            *reinterpret_cast<float4*>(&Xs[b][0][li][cg])      = v0;
            *reinterpret_cast<float4*>(&Xs[b][0][li][cg + 64]) = v1;
            if (!diag) {
                *reinterpret_cast<float4*>(&Xs[b][1][li][cg])      = v2;
                *reinterpret_cast<float4*>(&Xs[b][1][li][cg + 64]) = v3;
            }
        };

        // packed-fp32 accumulator: acc[ri][i][ci][jj] = cols {jj*2, jj*2+1}
        f2 acc[2][4][2][2] = {};

        float csum = 0.f;             // this thread's column sum
        const int side = diag ? 0 : (tid >> 7);   // colsum tile (diag: B==A)
        const int ccol  = tid & 127;

        // prologue: chunk 0 -> regs -> buf0 (idxbuf visible after scan barrier)
        LOADV(0);
        STORE_LDS(0);

        for (int ch = 0; ch < nchunks; ++ch) {
            const int cur = ch & 1;
            __syncthreads();          // buf[cur] visible; prev reads of buf[cur^1] done
            if (ch + 1 < nchunks) LOADV(ch + 1);   // loads fly under the FMA burst

            const float (*XA)[LSTR] = Xs[cur][0];
            const float (*XB)[LSTR] = diag ? Xs[cur][0] : Xs[cur][1];
            const int kn = min(KC, nc - ch * KC);
            for (int k = 0; k < kn; ++k) {
                float4 a0v = *reinterpret_cast<const float4*>(&XA[k][ty4]);
                float4 a1v = *reinterpret_cast<const float4*>(&XA[k][64 + ty4]);
                float4 b0v = *reinterpret_cast<const float4*>(&XB[k][tx4]);
                float4 b1v = *reinterpret_cast<const float4*>(&XB[k][64 + tx4]);
                float af[2][4] = {{a0v.x, a0v.y, a0v.z, a0v.w}, {a1v.x, a1v.y, a1v.z, a1v.w}};
                f2 bf[2][2];
                bf[0][0].x = b0v.x; bf[0][0].y = b0v.y;
                bf[0][1].x = b0v.z; bf[0][1].y = b0v.w;
                bf[1][0].x = b1v.x; bf[1][0].y = b1v.y;
                bf[1][1].x = b1v.z; bf[1][1].y = b1v.w;
                #pragma unroll
                for (int ri = 0; ri < 2; ++ri)
                    #pragma unroll
                    for (int i = 0; i < 4; ++i) {
                        f2 av; av.x = af[ri][i]; av.y = af[ri][i];
                        #pragma unroll
                        for (int ci = 0; ci < 2; ++ci) {
                            acc[ri][i][ci][0] = __builtin_elementwise_fma(av, bf[ci][0], acc[ri][i][ci][0]);
                            acc[ri][i][ci][1] = __builtin_elementwise_fma(av, bf[ci][1], acc[ri][i][ci][1]);
                        }
                    }
            }

            // column-sum pass on current buffer (zero-filled tail rows contribute 0)
            for (int k = 0; k < kn; ++k) csum += Xs[cur][side][k][ccol];

            if (ch + 1 < nchunks) STORE_LDS(cur ^ 1);    // waits vmcnt on LOADV regs
        }

        // mu / d arrays from per-thread column sums (tid<128: A-side, else B-side)
        {
            float mu = csum * ic;
            if (tid < 128) {
                muA[ccol] = mu;
                dA[ccol] = Ave_in[(size_t)c * A + a0 + ccol] - mu;
            } else {
                muB[ccol] = mu;
                dB[ccol] = Ave_in[(size_t)c * A + b0 + ccol] - mu;
            }
        }
        __syncthreads();

        float mb[2][4], db[2][4];
        #pragma unroll
        for (int ci = 0; ci < 2; ++ci)
            #pragma unroll
            for (int j = 0; j < 4; ++j) {
                mb[ci][j] = muB[ci * 64 + tx4 + j];
                db[ci][j] = dB[ci * 64 + tx4 + j];
            }

        // transform acc -> S = acc*s - w*muA*muB + w(1-w)*dA*dB (pure symmetric part)
        #pragma unroll
        for (int ri = 0; ri < 2; ++ri)
            #pragma unroll
            for (int i = 0; i < 4; ++i) {
                float ma = w  * muA[ri * 64 + ty4 + i];
                float da = aw * dA[ri * 64 + ty4 + i];
                #pragma unroll
                for (int ci = 0; ci < 2; ++ci) {
                    acc[ri][i][ci][0].x = acc[ri][i][ci][0].x * s - ma * mb[ci][0] + da * db[ci][0];
                    acc[ri][i][ci][0].y = acc[ri][i][ci][0].y * s - ma * mb[ci][1] + da * db[ci][1];
                    acc[ri][i][ci][1].x = acc[ri][i][ci][1].x * s - ma * mb[ci][2] + da * db[ci][2];
                    acc[ri][i][ci][1].y = acc[ri][i][ci][1].y * s - ma * mb[ci][3] + da * db[ci][3];
                }
            }

        // normal-orientation store: out[a][b] = S + omw*cov_in[a][b]
        #pragma unroll
        for (int ri = 0; ri < 2; ++ri)
            #pragma unroll
            for (int i = 0; i < 4; ++i) {
                const size_t rowo = cbase + (size_t)(a0 + ri * 64 + ty4 + i) * A + b0;
                #pragma unroll
                for (int ci = 0; ci < 2; ++ci) {
                    nf4 res;
                    res.x = acc[ri][i][ci][0].x;
                    res.y = acc[ri][i][ci][0].y;
                    res.z = acc[ri][i][ci][1].x;
                    res.w = acc[ri][i][ci][1].y;
                    if (omw != 0.f) {
                        float4 co = *reinterpret_cast<const float4*>(&cov_in[rowo + ci * 64 + tx4]);
                        res.x += co.x * omw; res.y += co.y * omw;
                        res.z += co.z * omw; res.w += co.w * omw;
                    }
                    __builtin_nontemporal_store(res,
                        reinterpret_cast<nf4*>(&out_cov[rowo + ci * 64 + tx4]));
                }
            }

        // mirror store via LDS transpose: out[b][a] = S^T + omw*cov_in[b][a]
        if (!diag) {
            float* tb = &Xs[0][0][0][0];     // reuse staging LDS (32*LSTR floats)
            #pragma unroll
            for (int cid = 0; cid < 4; ++cid) {           // 32 A-rows per chunk
                __syncthreads();                          // prev chunk reads done
                if ((ty >> 3) == (cid & 1)) {             // this thread owns chunk rows
                    const int rb = (ty & 7) * 4;          // local row base 0..28
                    #pragma unroll
                    for (int i = 0; i < 4; ++i)
                        #pragma unroll
                        for (int ci = 0; ci < 2; ++ci) {
                            float* t0 = &tb[(rb + i) * LSTR + ci * 64 + tx4];
                            t0[0] = acc[cid >> 1][i][ci][0].x;
                            t0[1] = acc[cid >> 1][i][ci][0].y;
                            t0[2] = acc[cid >> 1][i][ci][1].x;
                            t0[3] = acc[cid >> 1][i][ci][1].y;
                        }
                }
                __syncthreads();
                const int bc = tid >> 1;                  // out b-row 0..127
                const int ar0 = (tid & 1) << 4;           // 16-float half of the 32-row chunk
                const size_t orow = cbase + (size_t)(b0 + bc) * A + a0 + (cid << 5) + ar0;
                #pragma unroll
                for (int q = 0; q < 4; ++q) {
                    nf4 res;
                    res.x = tb[(ar0 + q * 4 + 0) * LSTR + bc];
                    res.y = tb[(ar0 + q * 4 + 1) * LSTR + bc];
                    res.z = tb[(ar0 + q * 4 + 2) * LSTR + bc];
                    res.w = tb[(ar0 + q * 4 + 3) * LSTR + bc];
                    if (omw != 0.f) {
                        float4 co = *reinterpret_cast<const float4*>(&cov_in[orow + q * 4]);
                        res.x += co.x * omw; res.y += co.y * omw;
                        res.z += co.z * omw; res.w += co.w * omw;
                    }
                    __builtin_nontemporal_store(res,
                        reinterpret_cast<nf4*>(&out_cov[orow + q * 4]));
                }
            }
        }
    } else {
        // w == 0: new_cov = cov_in * (1-w) for both orientations
        const int npass = diag ? 1 : 2;
        for (int p = 0; p < npass; ++p) {
            const int ra = p ? b0 : a0;
            const int cb = p ? a0 : b0;
            for (int t = tid; t < TM * TM / 4; t += 256) {
                const int r = t >> 5;
                const int c4 = (t & 31) * 4;
                const size_t o = cbase + (size_t)(ra + r) * A + cb + c4;
                float4 co = *reinterpret_cast<const float4*>(&cov_in[o]);
                nf4 res;
                res.x = co.x * omw; res.y = co.y * omw; res.z = co.z * omw; res.w = co.w * omw;
                __builtin_nontemporal_store(res, reinterpret_cast<nf4*>(&out_cov[o]));
            }
        }
    }
}

extern "C" void kernel_launch(void* const* d_in, const int* in_sizes, int n_in,
                              void* d_out, int out_size, void* d_ws, size_t ws_size,
                              hipStream_t stream) {
    const float* feats  = (const float*)d_in[0];
    const float* y_s    = (const float*)d_in[1];
    const float* cov_in = (const float*)d_in[2];
    const float* Ave_in = (const float*)d_in[3];
    const float* Amount = (const float*)d_in[4];
    const int*   labels = (const int*)d_in[5];

    const int C = in_sizes[4];
    const int N = in_sizes[5];
    const int A = in_sizes[3] / C;

    float* out      = (float*)d_out;
    float* out_loss = out;
    float* out_cov  = out + 1;
    float* out_ave  = out_cov + (size_t)C * A * A;
    float* out_amt  = out_ave + (size_t)C * A;

    hipMemsetAsync(out_loss, 0, sizeof(float), stream);   // loss accumulator init

    const int nt = A / TM;                    // 4 tile positions per axis
    const int npairs = nt * (nt + 1) / 2;     // 10 upper-triangle tile pairs
    const int AZ = (C + npairs - 1) / npairs; // ave-rider z-slices
    dim3 grid(npairs, 1, LZ + AZ + C);        // riders at low z: dispatch first
    mega_kernel<<<grid, 256, 0, stream>>>(feats, cov_in, Ave_in, y_s, labels, Amount,
                                          out_cov, out_ave, out_amt, out_loss,
                                          N, C, A, 1.f / (float)N, AZ);
}

// Round 8
// 284.670 us; speedup vs baseline: 1.0002x; 1.0002x over previous
//
#include <hip/hip_runtime.h>

// N=4096, A=512, C=100 (derived at launch).
// Outputs flat: [loss(1), new_cov(C*A*A), new_ave(C*A), new_amount(C)]
//
// ONE dispatch. Grid (NPAIRS, 1, LZ+AZ+C) where NPAIRS = T*(T+1)/2, T=A/TM:
//   z in [0,LZ)      : CE-loss rider blocks.
//   z in [LZ,LZ+AZ)  : new_ave rider blocks (one class per block; also new_amount).
//   z >= LZ+AZ       : cov tile-pair blocks, class c = z-LZ-AZ, blockIdx.x ->
//                      upper-triangle pair (ai<=bi). SYMMETRY: C[a][b]==C[b][a]
//                      bit-identically (same fp32 sum), so only 10 of 16 tiles
//                      are computed; off-diagonal tiles are mirrored via an LDS
//                      transpose + coalesced stores. Diagonal tiles stage only
//                      Xa (B-side aliases it): half the gather + LDS stores.
// Cov tile: RAW outer products (E[xx^T]-mu mu^T identity), REGISTER-staged
// float4 gather (DMA staging amplified HBM 4x in round 2 — keep feats L2-resident),
// LDS double-buffer -> ONE barrier per k-chunk, PACKED v_pk_fma_f32 inner loop,
// per-thread scalar column sums, label-scan member lists (no prep kernel),
// nontemporal streaming stores. cov_in folded at EPILOGUE; skipped when w==1.
//
// REGISTER PINNING: amdgpu_waves_per_eu(3,4). With 38.4KB LDS the occupancy cap
// is 4 blocks/CU regardless of VGPRs, but the plain-__launch_bounds__ allocator
// repeatedly (r2/r3/r7) targeted 8 waves/SIMD, squeezed VGPR to 64, and spilled
// the 64-float accumulator (+88..290 MB scratch HBM traffic, 2x dur). The (3,4)
// window forbids that: allocator settles ~104-170 VGPR, zero spill.

#define TM 128
#define KC 16      // members per k-chunk
#define LSTR 132   // padded LDS row stride (floats)
#define LZ 8       // loss z-slices

typedef float nf4 __attribute__((ext_vector_type(4)));   // nontemporal vector
typedef float f2  __attribute__((ext_vector_type(2)));   // packed-FMA pair

// ---------------- mega: loss riders + ave riders + cov ----------------
__global__ __launch_bounds__(256)
__attribute__((amdgpu_waves_per_eu(3, 4)))
void mega_kernel(
    const float* __restrict__ feats, const float* __restrict__ cov_in,
    const float* __restrict__ Ave_in, const float* __restrict__ y_s,
    const int* __restrict__ labels, const float* __restrict__ Amount,
    float* __restrict__ out_cov, float* __restrict__ out_ave,
    float* __restrict__ out_amt, float* __restrict__ out_loss0,
    int N, int C, int A, float invN, int AZ) {

    const int nxy = gridDim.x * gridDim.y;
    const int bxy = blockIdx.y * gridDim.x + blockIdx.x;
    const int tid = threadIdx.x;

    // ---- loss rider blocks (z in [0, LZ)) ----
    if ((int)blockIdx.z < LZ) {
        __shared__ float bsum[4];
        const int lane = tid & 63;
        const int wv = tid >> 6;
        const int bid = (int)blockIdx.z * nxy + bxy;
        const int nwaves = LZ * nxy * 4;
        const int gw = bid * 4 + wv;
        float wsum = 0.f;
        for (int r = gw; r < N; r += nwaves) {
            const float* row = y_s + (size_t)r * C;
            float m = -1e30f;
            for (int col = lane; col < C; col += 64) m = fmaxf(m, row[col]);
            #pragma unroll
            for (int off = 32; off > 0; off >>= 1) m = fmaxf(m, __shfl_xor(m, off));
            float se = 0.f;
            for (int col = lane; col < C; col += 64) se += __expf(row[col] - m);
            #pragma unroll
            for (int off = 32; off > 0; off >>= 1) se += __shfl_xor(se, off);
            if (lane == 0) wsum += -(row[labels[r]] - m - __logf(se));
        }
        if (lane == 0) bsum[wv] = wsum;
        __syncthreads();
        if (tid == 0)
            atomicAdd(out_loss0, (bsum[0] + bsum[1] + bsum[2] + bsum[3]) * invN);
        return;
    }

    // ---- ave rider blocks (z in [LZ, LZ+AZ)): one class per block ----
    if ((int)blockIdx.z < LZ + AZ) {
        __shared__ int idxs[256];
        __shared__ int acnt;
        const int bid = ((int)blockIdx.z - LZ) * nxy + bxy;
        if (bid >= C) return;
        const int c = bid;
        if (tid == 0) acnt = 0;
        __syncthreads();
        for (int i = tid; i < N; i += 256)
            if (labels[i] == c) { int p = atomicAdd(&acnt, 1); if (p < 256) idxs[p] = i; }
        __syncthreads();
        const int nc = min(acnt, 256);
        const float cf = (float)nc;
        const float ic = 1.f / fmaxf(cf, 1.f);
        const float am = Amount[c];
        const float dn = cf + am;
        const float w = dn > 0.f ? cf / dn : 0.f;
        if (tid == 0) out_amt[c] = am + cf;
        for (int c0 = 0; c0 < A; c0 += 512) {
            const int colA = c0 + tid;
            const int colB = c0 + 256 + tid;
            float s0 = 0.f, s1 = 0.f;
            int j = 0;
            for (; j + 3 < nc; j += 4) {
                const float* f0 = feats + (size_t)idxs[j] * A;
                const float* f1 = feats + (size_t)idxs[j + 1] * A;
                const float* f2p = feats + (size_t)idxs[j + 2] * A;
                const float* f3 = feats + (size_t)idxs[j + 3] * A;
                if (colA < A) s0 += f0[colA] + f1[colA] + f2p[colA] + f3[colA];
                if (colB < A) s1 += f0[colB] + f1[colB] + f2p[colB] + f3[colB];
            }
            for (; j < nc; ++j) {
                const float* fr = feats + (size_t)idxs[j] * A;
                if (colA < A) s0 += fr[colA];
                if (colB < A) s1 += fr[colB];
            }
            if (colA < A)
                out_ave[(size_t)c * A + colA] =
                    Ave_in[(size_t)c * A + colA] * (1.f - w) + (s0 * ic) * w;
            if (colB < A)
                out_ave[(size_t)c * A + colB] =
                    Ave_in[(size_t)c * A + colB] * (1.f - w) + (s1 * ic) * w;
        }
        return;
    }

    // ---- cov tile-pair: class c, upper-triangle pair (ai<=bi) ----
    const int c  = (int)blockIdx.z - LZ - AZ;
    // map blockIdx.x -> (ai,bi), ai<=bi, row-major upper triangle
    int ai = 0, rem = (int)blockIdx.x, span = A / TM;
    while (rem >= span) { rem -= span; ++ai; --span; }
    const int bi = ai + rem;
    const bool diag = (ai == bi);
    const int a0 = ai * TM;
    const int b0 = bi * TM;

    // [buf][0=A-tile,1=B-tile][k][col], padded stride
    __shared__ float Xs[2][2][KC][LSTR];
    __shared__ float muA[TM], muB[TM], dA[TM], dB[TM];
    __shared__ int idxbuf[256];
    __shared__ int ccnt;

    const int ty = tid >> 4, tx = tid & 15;
    const int ty4 = ty * 4, tx4 = tx * 4;

    // scan labels -> member list for class c (L2-resident 16KB)
    if (tid == 0) ccnt = 0;
    __syncthreads();
    for (int i = tid; i < N; i += 256)
        if (labels[i] == c) { int p = atomicAdd(&ccnt, 1); if (p < 256) idxbuf[p] = i; }
    __syncthreads();
    const int nc = min(ccnt, 256);

    const float cf  = (float)nc;
    const float ic  = 1.f / fmaxf(cf, 1.f);
    const float am  = Amount[c];
    const float dn  = cf + am;
    const float w   = dn > 0.f ? cf / dn : 0.f;
    const float omw = 1.f - w;
    const float s   = ic * w;
    const float aw  = w * omw;
    const size_t cbase = (size_t)c * A * A;

    if (s > 0.f) {
        const int nchunks = (nc + KC - 1) / KC;
        const int li = ty;            // staging member row (0..15)
        const int cg = tx4;           // staging col group

        float4 v0, v1, v2, v3;        // pipeline registers (RAW values)
        auto LOADV = [&](int ch) {
            const int slot = ch * KC + li;
            v0 = make_float4(0.f, 0.f, 0.f, 0.f); v1 = v0; v2 = v0; v3 = v0;
            if (slot < nc) {
                int row = idxbuf[slot];
                const float* fr = feats + (size_t)row * A;
                v0 = *reinterpret_cast<const float4*>(fr + a0 + cg);
                v1 = *reinterpret_cast<const float4*>(fr + a0 + cg + 64);
                if (!diag) {
                    v2 = *reinterpret_cast<const float4*>(fr + b0 + cg);
                    v3 = *reinterpret_cast<const float4*>(fr + b0 + cg + 64);
                }
            }
        };
        auto STORE_LDS = [&](int b) {
            *reinterpret_cast<float4*>(&Xs[b][0][li][cg])      = v0;
            *reinterpret_cast<float4*>(&Xs[b][0][li][cg + 64]) = v1;
            if (!diag) {
                *reinterpret_cast<float4*>(&Xs[b][1][li][cg])      = v2;
                *reinterpret_cast<float4*>(&Xs[b][1][li][cg + 64]) = v3;
            }
        };

        // packed-fp32 accumulator: acc[ri][i][ci][jj] = cols {jj*2, jj*2+1}
        f2 acc[2][4][2][2] = {};

        float csum = 0.f;             // this thread's column sum
        const int side = diag ? 0 : (tid >> 7);   // colsum tile (diag: B==A)
        const int ccol  = tid & 127;

        // prologue: chunk 0 -> regs -> buf0 (idxbuf visible after scan barrier)
        LOADV(0);
        STORE_LDS(0);

        for (int ch = 0; ch < nchunks; ++ch) {
            const int cur = ch & 1;
            __syncthreads();          // buf[cur] visible; prev reads of buf[cur^1] done
            if (ch + 1 < nchunks) LOADV(ch + 1);   // loads fly under the FMA burst

            const float (*XA)[LSTR] = Xs[cur][0];
            const float (*XB)[LSTR] = diag ? Xs[cur][0] : Xs[cur][1];
            const int kn = min(KC, nc - ch * KC);
            if (kn == KC) {
                #pragma unroll
                for (int k = 0; k < KC; ++k) {
                    float4 a0v = *reinterpret_cast<const float4*>(&XA[k][ty4]);
                    float4 a1v = *reinterpret_cast<const float4*>(&XA[k][64 + ty4]);
                    float4 b0v = *reinterpret_cast<const float4*>(&XB[k][tx4]);
                    float4 b1v = *reinterpret_cast<const float4*>(&XB[k][64 + tx4]);
                    float af[2][4] = {{a0v.x, a0v.y, a0v.z, a0v.w}, {a1v.x, a1v.y, a1v.z, a1v.w}};
                    f2 bf[2][2];
                    bf[0][0].x = b0v.x; bf[0][0].y = b0v.y;
                    bf[0][1].x = b0v.z; bf[0][1].y = b0v.w;
                    bf[1][0].x = b1v.x; bf[1][0].y = b1v.y;
                    bf[1][1].x = b1v.z; bf[1][1].y = b1v.w;
                    #pragma unroll
                    for (int ri = 0; ri < 2; ++ri)
                        #pragma unroll
                        for (int i = 0; i < 4; ++i) {
                            f2 av; av.x = af[ri][i]; av.y = af[ri][i];
                            #pragma unroll
                            for (int ci = 0; ci < 2; ++ci) {
                                acc[ri][i][ci][0] = __builtin_elementwise_fma(av, bf[ci][0], acc[ri][i][ci][0]);
                                acc[ri][i][ci][1] = __builtin_elementwise_fma(av, bf[ci][1], acc[ri][i][ci][1]);
                            }
                        }
                }
            } else {
                for (int k = 0; k < kn; ++k) {
                    float4 a0v = *reinterpret_cast<const float4*>(&XA[k][ty4]);
                    float4 a1v = *reinterpret_cast<const float4*>(&XA[k][64 + ty4]);
                    float4 b0v = *reinterpret_cast<const float4*>(&XB[k][tx4]);
                    float4 b1v = *reinterpret_cast<const float4*>(&XB[k][64 + tx4]);
                    float af[2][4] = {{a0v.x, a0v.y, a0v.z, a0v.w}, {a1v.x, a1v.y, a1v.z, a1v.w}};
                    f2 bf[2][2];
                    bf[0][0].x = b0v.x; bf[0][0].y = b0v.y;
                    bf[0][1].x = b0v.z; bf[0][1].y = b0v.w;
                    bf[1][0].x = b1v.x; bf[1][0].y = b1v.y;
                    bf[1][1].x = b1v.z; bf[1][1].y = b1v.w;
                    #pragma unroll
                    for (int ri = 0; ri < 2; ++ri)
                        #pragma unroll
                        for (int i = 0; i < 4; ++i) {
                            f2 av; av.x = af[ri][i]; av.y = af[ri][i];
                            #pragma unroll
                            for (int ci = 0; ci < 2; ++ci) {
                                acc[ri][i][ci][0] = __builtin_elementwise_fma(av, bf[ci][0], acc[ri][i][ci][0]);
                                acc[ri][i][ci][1] = __builtin_elementwise_fma(av, bf[ci][1], acc[ri][i][ci][1]);
                            }
                        }
                }
            }

            // column-sum pass on current buffer (zero-filled tail rows contribute 0)
            for (int k = 0; k < kn; ++k) csum += Xs[cur][side][k][ccol];

            if (ch + 1 < nchunks) STORE_LDS(cur ^ 1);    // waits vmcnt on LOADV regs
        }

        // mu / d arrays from per-thread column sums (tid<128: A-side, else B-side)
        {
            float mu = csum * ic;
            if (tid < 128) {
                muA[ccol] = mu;
                dA[ccol] = Ave_in[(size_t)c * A + a0 + ccol] - mu;
            } else {
                muB[ccol] = mu;
                dB[ccol] = Ave_in[(size_t)c * A + b0 + ccol] - mu;
            }
        }
        __syncthreads();

        float mb[2][4], db[2][4];
        #pragma unroll
        for (int ci = 0; ci < 2; ++ci)
            #pragma unroll
            for (int j = 0; j < 4; ++j) {
                mb[ci][j] = muB[ci * 64 + tx4 + j];
                db[ci][j] = dB[ci * 64 + tx4 + j];
            }

        // transform acc -> S = acc*s - w*muA*muB + w(1-w)*dA*dB (pure symmetric part)
        #pragma unroll
        for (int ri = 0; ri < 2; ++ri)
            #pragma unroll
            for (int i = 0; i < 4; ++i) {
                float ma = w  * muA[ri * 64 + ty4 + i];
                float da = aw * dA[ri * 64 + ty4 + i];
                #pragma unroll
                for (int ci = 0; ci < 2; ++ci) {
                    acc[ri][i][ci][0].x = acc[ri][i][ci][0].x * s - ma * mb[ci][0] + da * db[ci][0];
                    acc[ri][i][ci][0].y = acc[ri][i][ci][0].y * s - ma * mb[ci][1] + da * db[ci][1];
                    acc[ri][i][ci][1].x = acc[ri][i][ci][1].x * s - ma * mb[ci][2] + da * db[ci][2];
                    acc[ri][i][ci][1].y = acc[ri][i][ci][1].y * s - ma * mb[ci][3] + da * db[ci][3];
                }
            }

        // normal-orientation store: out[a][b] = S + omw*cov_in[a][b]
        #pragma unroll
        for (int ri = 0; ri < 2; ++ri)
            #pragma unroll
            for (int i = 0; i < 4; ++i) {
                const size_t rowo = cbase + (size_t)(a0 + ri * 64 + ty4 + i) * A + b0;
                #pragma unroll
                for (int ci = 0; ci < 2; ++ci) {
                    nf4 res;
                    res.x = acc[ri][i][ci][0].x;
                    res.y = acc[ri][i][ci][0].y;
                    res.z = acc[ri][i][ci][1].x;
                    res.w = acc[ri][i][ci][1].y;
                    if (omw != 0.f) {
                        float4 co = *reinterpret_cast<const float4*>(&cov_in[rowo + ci * 64 + tx4]);
                        res.x += co.x * omw; res.y += co.y * omw;
                        res.z += co.z * omw; res.w += co.w * omw;
                    }
                    __builtin_nontemporal_store(res,
                        reinterpret_cast<nf4*>(&out_cov[rowo + ci * 64 + tx4]));
                }
            }

        // mirror store via LDS transpose: out[b][a] = S^T + omw*cov_in[b][a]
        if (!diag) {
            float* tb = &Xs[0][0][0][0];     // reuse staging LDS (32*LSTR floats)
            #pragma unroll
            for (int cid = 0; cid < 4; ++cid) {           // 32 A-rows per chunk
                __syncthreads();                          // prev chunk reads done
                if ((ty >> 3) == (cid & 1)) {             // this thread owns chunk rows
                    const int rb = (ty & 7) * 4;          // local row base 0..28
                    #pragma unroll
                    for (int i = 0; i < 4; ++i)
                        #pragma unroll
                        for (int ci = 0; ci < 2; ++ci) {
                            float* t0 = &tb[(rb + i) * LSTR + ci * 64 + tx4];
                            t0[0] = acc[cid >> 1][i][ci][0].x;
                            t0[1] = acc[cid >> 1][i][ci][0].y;
                            t0[2] = acc[cid >> 1][i][ci][1].x;
                            t0[3] = acc[cid >> 1][i][ci][1].y;
                        }
                }
                __syncthreads();
                const int bc = tid >> 1;                  // out b-row 0..127
                const int ar0 = (tid & 1) << 4;           // 16-float half of the 32-row chunk
                const size_t orow = cbase + (size_t)(b0 + bc) * A + a0 + (cid << 5) + ar0;
                #pragma unroll
                for (int q = 0; q < 4; ++q) {
                    nf4 res;
                    res.x = tb[(ar0 + q * 4 + 0) * LSTR + bc];
                    res.y = tb[(ar0 + q * 4 + 1) * LSTR + bc];
                    res.z = tb[(ar0 + q * 4 + 2) * LSTR + bc];
                    res.w = tb[(ar0 + q * 4 + 3) * LSTR + bc];
                    if (omw != 0.f) {
                        float4 co = *reinterpret_cast<const float4*>(&cov_in[orow + q * 4]);
                        res.x += co.x * omw; res.y += co.y * omw;
                        res.z += co.z * omw; res.w += co.w * omw;
                    }
                    __builtin_nontemporal_store(res,
                        reinterpret_cast<nf4*>(&out_cov[orow + q * 4]));
                }
            }
        }
    } else {
        // w == 0: new_cov = cov_in * (1-w) for both orientations
        const int npass = diag ? 1 : 2;
        for (int p = 0; p < npass; ++p) {
            const int ra = p ? b0 : a0;
            const int cb = p ? a0 : b0;
            for (int t = tid; t < TM * TM / 4; t += 256) {
                const int r = t >> 5;
                const int c4 = (t & 31) * 4;
                const size_t o = cbase + (size_t)(ra + r) * A + cb + c4;
                float4 co = *reinterpret_cast<const float4*>(&cov_in[o]);
                nf4 res;
                res.x = co.x * omw; res.y = co.y * omw; res.z = co.z * omw; res.w = co.w * omw;
                __builtin_nontemporal_store(res, reinterpret_cast<nf4*>(&out_cov[o]));
            }
        }
    }
}

extern "C" void kernel_launch(void* const* d_in, const int* in_sizes, int n_in,
                              void* d_out, int out_size, void* d_ws, size_t ws_size,
                              hipStream_t stream) {
    const float* feats  = (const float*)d_in[0];
    const float* y_s    = (const float*)d_in[1];
    const float* cov_in = (const float*)d_in[2];
    const float* Ave_in = (const float*)d_in[3];
    const float* Amount = (const float*)d_in[4];
    const int*   labels = (const int*)d_in[5];

    const int C = in_sizes[4];
    const int N = in_sizes[5];
    const int A = in_sizes[3] / C;

    float* out      = (float*)d_out;
    float* out_loss = out;
    float* out_cov  = out + 1;
    float* out_ave  = out_cov + (size_t)C * A * A;
    float* out_amt  = out_ave + (size_t)C * A;

    hipMemsetAsync(out_loss, 0, sizeof(float), stream);   // loss accumulator init

    const int nt = A / TM;                    // 4 tile positions per axis
    const int npairs = nt * (nt + 1) / 2;     // 10 upper-triangle tile pairs
    const int AZ = (C + npairs - 1) / npairs; // ave-rider z-slices
    dim3 grid(npairs, 1, LZ + AZ + C);        // riders at low z: dispatch first
    mega_kernel<<<grid, 256, 0, stream>>>(feats, cov_in, Ave_in, y_s, labels, Amount,
                                          out_cov, out_ave, out_amt, out_loss,
                                          N, C, A, 1.f / (float)N, AZ);
}

// Round 9
// 228.836 us; speedup vs baseline: 1.2442x; 1.2440x over previous
//
#include <hip/hip_runtime.h>

// N=4096, A=512, C=100 (derived at launch).
// Outputs flat: [loss(1), new_cov(C*A*A), new_ave(C*A), new_amount(C)]
//
// ONE dispatch. Grid (NPAIRS, 1, LZ+AZ+C), NPAIRS = T*(T+1)/2, T=A/TM:
//   z in [0,LZ)      : CE-loss rider blocks.
//   z in [LZ,LZ+AZ)  : new_ave rider blocks (one class per block; also new_amount).
//   z >= LZ+AZ       : cov tile-pair blocks, class c = z-LZ-AZ, blockIdx.x ->
//                      upper-triangle pair (ai<=bi). SYMMETRY: C[a][b]==C[b][a]
//                      bit-identically, so only 10 of 16 tiles are computed.
// Cov tile: identical to the proven round-6 structure (VGPR=104, no spill):
//   RAW outer products (E[xx^T]-mu mu^T), register-staged float4 gather,
//   LDS double-buffer, one barrier per k-chunk, packed v_pk_fma_f32,
//   UNCONDITIONAL two-sided staging (diag stages duplicate data — keeps the
//   staging/k-loop codegen byte-identical to r6; no runtime LDS pointers).
// Epilogue (the r7/r8 spill fix): transform + normal-store + transpose-stash
// proceed per 32-a-row CHUNK, so each quarter of acc dies as it is consumed
// (pressure 64->48->32->16 instead of 64 held across the whole mirror loop).
// Chunk ownership (ty>>3)==(cid&1) is wave-uniform -> no divergence.
// Mirror store reads the stashed S from LDS (+ omw*cov_in[b][a] when w<1),
// cached float4 stores (L2 merges partial lines). cov_in folded at epilogue;
// skipped when w==1 (always true for Amount=0 inputs).
//
// NOTE: plain __launch_bounds__(256) ONLY. (256,4) and waves_per_eu(3,4) both
// let/made the allocator squeeze below the 64-float accumulator (VGPR 64/84)
// and spill (+88..106 MB scratch HBM traffic, ~2x dur) — r3/r7/r8.

#define TM 128
#define KC 16      // members per k-chunk
#define LSTR 132   // padded LDS row stride (floats)
#define LZ 8       // loss z-slices

typedef float nf4 __attribute__((ext_vector_type(4)));   // nontemporal vector
typedef float f2  __attribute__((ext_vector_type(2)));   // packed-FMA pair

// ---------------- mega: loss riders + ave riders + cov ----------------
__global__ __launch_bounds__(256) void mega_kernel(
    const float* __restrict__ feats, const float* __restrict__ cov_in,
    const float* __restrict__ Ave_in, const float* __restrict__ y_s,
    const int* __restrict__ labels, const float* __restrict__ Amount,
    float* __restrict__ out_cov, float* __restrict__ out_ave,
    float* __restrict__ out_amt, float* __restrict__ out_loss0,
    int N, int C, int A, float invN, int AZ) {

    const int nxy = gridDim.x * gridDim.y;
    const int bxy = blockIdx.y * gridDim.x + blockIdx.x;
    const int tid = threadIdx.x;

    // ---- loss rider blocks (z in [0, LZ)) ----
    if ((int)blockIdx.z < LZ) {
        __shared__ float bsum[4];
        const int lane = tid & 63;
        const int wv = tid >> 6;
        const int bid = (int)blockIdx.z * nxy + bxy;
        const int nwaves = LZ * nxy * 4;
        const int gw = bid * 4 + wv;
        float wsum = 0.f;
        for (int r = gw; r < N; r += nwaves) {
            const float* row = y_s + (size_t)r * C;
            float m = -1e30f;
            for (int col = lane; col < C; col += 64) m = fmaxf(m, row[col]);
            #pragma unroll
            for (int off = 32; off > 0; off >>= 1) m = fmaxf(m, __shfl_xor(m, off));
            float se = 0.f;
            for (int col = lane; col < C; col += 64) se += __expf(row[col] - m);
            #pragma unroll
            for (int off = 32; off > 0; off >>= 1) se += __shfl_xor(se, off);
            if (lane == 0) wsum += -(row[labels[r]] - m - __logf(se));
        }
        if (lane == 0) bsum[wv] = wsum;
        __syncthreads();
        if (tid == 0)
            atomicAdd(out_loss0, (bsum[0] + bsum[1] + bsum[2] + bsum[3]) * invN);
        return;
    }

    // ---- ave rider blocks (z in [LZ, LZ+AZ)): one class per block ----
    if ((int)blockIdx.z < LZ + AZ) {
        __shared__ int idxs[256];
        __shared__ int acnt;
        const int bid = ((int)blockIdx.z - LZ) * nxy + bxy;
        if (bid >= C) return;
        const int c = bid;
        if (tid == 0) acnt = 0;
        __syncthreads();
        for (int i = tid; i < N; i += 256)
            if (labels[i] == c) { int p = atomicAdd(&acnt, 1); if (p < 256) idxs[p] = i; }
        __syncthreads();
        const int nc = min(acnt, 256);
        const float cf = (float)nc;
        const float ic = 1.f / fmaxf(cf, 1.f);
        const float am = Amount[c];
        const float dn = cf + am;
        const float w = dn > 0.f ? cf / dn : 0.f;
        if (tid == 0) out_amt[c] = am + cf;
        for (int c0 = 0; c0 < A; c0 += 512) {
            const int colA = c0 + tid;
            const int colB = c0 + 256 + tid;
            float s0 = 0.f, s1 = 0.f;
            int j = 0;
            for (; j + 3 < nc; j += 4) {
                const float* f0 = feats + (size_t)idxs[j] * A;
                const float* f1 = feats + (size_t)idxs[j + 1] * A;
                const float* f2p = feats + (size_t)idxs[j + 2] * A;
                const float* f3 = feats + (size_t)idxs[j + 3] * A;
                if (colA < A) s0 += f0[colA] + f1[colA] + f2p[colA] + f3[colA];
                if (colB < A) s1 += f0[colB] + f1[colB] + f2p[colB] + f3[colB];
            }
            for (; j < nc; ++j) {
                const float* fr = feats + (size_t)idxs[j] * A;
                if (colA < A) s0 += fr[colA];
                if (colB < A) s1 += fr[colB];
            }
            if (colA < A)
                out_ave[(size_t)c * A + colA] =
                    Ave_in[(size_t)c * A + colA] * (1.f - w) + (s0 * ic) * w;
            if (colB < A)
                out_ave[(size_t)c * A + colB] =
                    Ave_in[(size_t)c * A + colB] * (1.f - w) + (s1 * ic) * w;
        }
        return;
    }

    // ---- cov tile-pair: class c, upper-triangle pair (ai<=bi) ----
    const int c  = (int)blockIdx.z - LZ - AZ;
    int ai = 0, rem = (int)blockIdx.x, span = A / TM;
    while (rem >= span) { rem -= span; ++ai; --span; }
    const int bi = ai + rem;
    const bool diag = (ai == bi);
    const int a0 = ai * TM;
    const int b0 = bi * TM;

    // [buf][0=A-tile,1=B-tile][k][col], padded stride
    __shared__ float Xs[2][2][KC][LSTR];
    __shared__ float muA[TM], muB[TM], dA[TM], dB[TM];
    __shared__ int idxbuf[256];
    __shared__ int ccnt;

    const int ty = tid >> 4, tx = tid & 15;
    const int ty4 = ty * 4, tx4 = tx * 4;

    // scan labels -> member list for class c (L2-resident 16KB)
    if (tid == 0) ccnt = 0;
    __syncthreads();
    for (int i = tid; i < N; i += 256)
        if (labels[i] == c) { int p = atomicAdd(&ccnt, 1); if (p < 256) idxbuf[p] = i; }
    __syncthreads();
    const int nc = min(ccnt, 256);

    const float cf  = (float)nc;
    const float ic  = 1.f / fmaxf(cf, 1.f);
    const float am  = Amount[c];
    const float dn  = cf + am;
    const float w   = dn > 0.f ? cf / dn : 0.f;
    const float omw = 1.f - w;
    const float s   = ic * w;
    const float aw  = w * omw;
    const size_t cbase = (size_t)c * A * A;

    if (s > 0.f) {
        const int nchunks = (nc + KC - 1) / KC;
        const int li = ty;            // staging member row (0..15)
        const int cg = tx4;           // staging col group

        float4 v0, v1, v2, v3;        // pipeline registers (RAW values)
        auto LOADV = [&](int ch) {
            const int slot = ch * KC + li;
            v0 = make_float4(0.f, 0.f, 0.f, 0.f); v1 = v0; v2 = v0; v3 = v0;
            if (slot < nc) {
                int row = idxbuf[slot];
                const float* fr = feats + (size_t)row * A;
                v0 = *reinterpret_cast<const float4*>(fr + a0 + cg);
                v1 = *reinterpret_cast<const float4*>(fr + a0 + cg + 64);
                v2 = *reinterpret_cast<const float4*>(fr + b0 + cg);
                v3 = *reinterpret_cast<const float4*>(fr + b0 + cg + 64);
            }
        };
        auto STORE_LDS = [&](int b) {
            *reinterpret_cast<float4*>(&Xs[b][0][li][cg])      = v0;
            *reinterpret_cast<float4*>(&Xs[b][0][li][cg + 64]) = v1;
            *reinterpret_cast<float4*>(&Xs[b][1][li][cg])      = v2;
            *reinterpret_cast<float4*>(&Xs[b][1][li][cg + 64]) = v3;
        };

        // packed-fp32 accumulator: acc[ri][i][ci][jj] = cols {jj*2, jj*2+1}
        f2 acc[2][4][2][2] = {};

        float csum = 0.f;             // this thread's column sum
        const int cside = tid >> 7;   // 0: A-tile, 1: B-tile
        const int ccol  = tid & 127;

        // prologue: chunk 0 -> regs -> buf0 (idxbuf visible after scan barrier)
        LOADV(0);
        STORE_LDS(0);

        for (int ch = 0; ch < nchunks; ++ch) {
            const int cur = ch & 1;
            __syncthreads();          // buf[cur] visible; prev reads of buf[cur^1] done
            if (ch + 1 < nchunks) LOADV(ch + 1);   // loads fly under the FMA burst

            const int kn = min(KC, nc - ch * KC);
            if (kn == KC) {
                #pragma unroll
                for (int k = 0; k < KC; ++k) {
                    float4 a0v = *reinterpret_cast<const float4*>(&Xs[cur][0][k][ty4]);
                    float4 a1v = *reinterpret_cast<const float4*>(&Xs[cur][0][k][64 + ty4]);
                    float4 b0v = *reinterpret_cast<const float4*>(&Xs[cur][1][k][tx4]);
                    float4 b1v = *reinterpret_cast<const float4*>(&Xs[cur][1][k][64 + tx4]);
                    float af[2][4] = {{a0v.x, a0v.y, a0v.z, a0v.w}, {a1v.x, a1v.y, a1v.z, a1v.w}};
                    f2 bf[2][2];
                    bf[0][0].x = b0v.x; bf[0][0].y = b0v.y;
                    bf[0][1].x = b0v.z; bf[0][1].y = b0v.w;
                    bf[1][0].x = b1v.x; bf[1][0].y = b1v.y;
                    bf[1][1].x = b1v.z; bf[1][1].y = b1v.w;
                    #pragma unroll
                    for (int ri = 0; ri < 2; ++ri)
                        #pragma unroll
                        for (int i = 0; i < 4; ++i) {
                            f2 av; av.x = af[ri][i]; av.y = af[ri][i];
                            #pragma unroll
                            for (int ci = 0; ci < 2; ++ci) {
                                acc[ri][i][ci][0] = __builtin_elementwise_fma(av, bf[ci][0], acc[ri][i][ci][0]);
                                acc[ri][i][ci][1] = __builtin_elementwise_fma(av, bf[ci][1], acc[ri][i][ci][1]);
                            }
                        }
                }
            } else {
                for (int k = 0; k < kn; ++k) {
                    float4 a0v = *reinterpret_cast<const float4*>(&Xs[cur][0][k][ty4]);
                    float4 a1v = *reinterpret_cast<const float4*>(&Xs[cur][0][k][64 + ty4]);
                    float4 b0v = *reinterpret_cast<const float4*>(&Xs[cur][1][k][tx4]);
                    float4 b1v = *reinterpret_cast<const float4*>(&Xs[cur][1][k][64 + tx4]);
                    float af[2][4] = {{a0v.x, a0v.y, a0v.z, a0v.w}, {a1v.x, a1v.y, a1v.z, a1v.w}};
                    f2 bf[2][2];
                    bf[0][0].x = b0v.x; bf[0][0].y = b0v.y;
                    bf[0][1].x = b0v.z; bf[0][1].y = b0v.w;
                    bf[1][0].x = b1v.x; bf[1][0].y = b1v.y;
                    bf[1][1].x = b1v.z; bf[1][1].y = b1v.w;
                    #pragma unroll
                    for (int ri = 0; ri < 2; ++ri)
                        #pragma unroll
                        for (int i = 0; i < 4; ++i) {
                            f2 av; av.x = af[ri][i]; av.y = af[ri][i];
                            #pragma unroll
                            for (int ci = 0; ci < 2; ++ci) {
                                acc[ri][i][ci][0] = __builtin_elementwise_fma(av, bf[ci][0], acc[ri][i][ci][0]);
                                acc[ri][i][ci][1] = __builtin_elementwise_fma(av, bf[ci][1], acc[ri][i][ci][1]);
                            }
                        }
                }
            }

            // column-sum pass on current buffer (zero-filled tail rows contribute 0)
            for (int k = 0; k < kn; ++k) csum += Xs[cur][cside][k][ccol];

            if (ch + 1 < nchunks) STORE_LDS(cur ^ 1);    // waits vmcnt on LOADV regs
        }

        // mu / d arrays from per-thread column sums (tid<128: A-side, else B-side)
        {
            float mu = csum * ic;
            if (tid < 128) {
                muA[ccol] = mu;
                dA[ccol] = Ave_in[(size_t)c * A + a0 + ccol] - mu;
            } else {
                muB[ccol] = mu;
                dB[ccol] = Ave_in[(size_t)c * A + b0 + ccol] - mu;
            }
        }
        __syncthreads();              // also: last Xs (staging) reads complete

        float mb[2][4], db[2][4];
        #pragma unroll
        for (int ci = 0; ci < 2; ++ci)
            #pragma unroll
            for (int j = 0; j < 4; ++j) {
                mb[ci][j] = muB[ci * 64 + tx4 + j];
                db[ci][j] = dB[ci * 64 + tx4 + j];
            }

        if (diag) {
            // r6-style one-pass epilogue (no mirror needed)
            #pragma unroll
            for (int ri = 0; ri < 2; ++ri)
                #pragma unroll
                for (int i = 0; i < 4; ++i) {
                    float ma = w  * muA[ri * 64 + ty4 + i];
                    float da = aw * dA[ri * 64 + ty4 + i];
                    const size_t rowo = cbase + (size_t)(a0 + ri * 64 + ty4 + i) * A + b0;
                    #pragma unroll
                    for (int ci = 0; ci < 2; ++ci) {
                        nf4 res;
                        res.x = acc[ri][i][ci][0].x * s - ma * mb[ci][0] + da * db[ci][0];
                        res.y = acc[ri][i][ci][0].y * s - ma * mb[ci][1] + da * db[ci][1];
                        res.z = acc[ri][i][ci][1].x * s - ma * mb[ci][2] + da * db[ci][2];
                        res.w = acc[ri][i][ci][1].y * s - ma * mb[ci][3] + da * db[ci][3];
                        if (omw != 0.f) {
                            float4 co = *reinterpret_cast<const float4*>(&cov_in[rowo + ci * 64 + tx4]);
                            res.x += co.x * omw; res.y += co.y * omw;
                            res.z += co.z * omw; res.w += co.w * omw;
                        }
                        __builtin_nontemporal_store(res,
                            reinterpret_cast<nf4*>(&out_cov[rowo + ci * 64 + tx4]));
                    }
                }
        } else {
            // chunked epilogue: each 32-a-row chunk consumes its quarter of acc
            // (transform + normal store + stash S in LDS), then mirror-stores it.
            float* tb = &Xs[0][0][0][0];     // 32 x LSTR floats, reuse staging LDS
            #pragma unroll
            for (int cid = 0; cid < 4; ++cid) {
                const int ri = cid >> 1;
                if ((ty >> 3) == (cid & 1)) {            // wave-uniform ownership
                    #pragma unroll
                    for (int i = 0; i < 4; ++i) {
                        const int lr = (ty & 7) * 4 + i; // local a-row in chunk
                        float ma = w  * muA[ri * 64 + ty4 + i];
                        float da = aw * dA[ri * 64 + ty4 + i];
                        const size_t rowo = cbase + (size_t)(a0 + cid * 32 + lr) * A + b0;
                        #pragma unroll
                        for (int ci = 0; ci < 2; ++ci) {
                            float S0 = acc[ri][i][ci][0].x * s - ma * mb[ci][0] + da * db[ci][0];
                            float S1 = acc[ri][i][ci][0].y * s - ma * mb[ci][1] + da * db[ci][1];
                            float S2 = acc[ri][i][ci][1].x * s - ma * mb[ci][2] + da * db[ci][2];
                            float S3 = acc[ri][i][ci][1].y * s - ma * mb[ci][3] + da * db[ci][3];
                            float* t0 = &tb[lr * LSTR + ci * 64 + tx4];
                            t0[0] = S0; t0[1] = S1; t0[2] = S2; t0[3] = S3;
                            nf4 res; res.x = S0; res.y = S1; res.z = S2; res.w = S3;
                            if (omw != 0.f) {
                                float4 co = *reinterpret_cast<const float4*>(&cov_in[rowo + ci * 64 + tx4]);
                                res.x += co.x * omw; res.y += co.y * omw;
                                res.z += co.z * omw; res.w += co.w * omw;
                            }
                            __builtin_nontemporal_store(res,
                                reinterpret_cast<nf4*>(&out_cov[rowo + ci * 64 + tx4]));
                        }
                    }
                }
                __syncthreads();                          // tb chunk ready
                {   // mirror store: out[b0+bc][a0 + cid*32 + ar0 + 0..15], all threads
                    const int bc = tid >> 1;
                    const int ar0 = (tid & 1) << 4;
                    const size_t orow = cbase + (size_t)(b0 + bc) * A + a0 + cid * 32 + ar0;
                    #pragma unroll
                    for (int q = 0; q < 4; ++q) {
                        float4 res;
                        res.x = tb[(ar0 + q * 4 + 0) * LSTR + bc];
                        res.y = tb[(ar0 + q * 4 + 1) * LSTR + bc];
                        res.z = tb[(ar0 + q * 4 + 2) * LSTR + bc];
                        res.w = tb[(ar0 + q * 4 + 3) * LSTR + bc];
                        if (omw != 0.f) {
                            float4 co = *reinterpret_cast<const float4*>(&cov_in[orow + q * 4]);
                            res.x += co.x * omw; res.y += co.y * omw;
                            res.z += co.z * omw; res.w += co.w * omw;
                        }
                        *reinterpret_cast<float4*>(&out_cov[orow + q * 4]) = res;  // cached
                    }
                }
                __syncthreads();                          // mirror reads done before next stash
            }
        }
    } else {
        // w == 0: new_cov = cov_in * (1-w) for both orientations
        const int npass = diag ? 1 : 2;
        for (int p = 0; p < npass; ++p) {
            const int ra = p ? b0 : a0;
            const int cb = p ? a0 : b0;
            for (int t = tid; t < TM * TM / 4; t += 256) {
                const int r = t >> 5;
                const int c4 = (t & 31) * 4;
                const size_t o = cbase + (size_t)(ra + r) * A + cb + c4;
                float4 co = *reinterpret_cast<const float4*>(&cov_in[o]);
                nf4 res;
                res.x = co.x * omw; res.y = co.y * omw; res.z = co.z * omw; res.w = co.w * omw;
                __builtin_nontemporal_store(res, reinterpret_cast<nf4*>(&out_cov[o]));
            }
        }
    }
}

extern "C" void kernel_launch(void* const* d_in, const int* in_sizes, int n_in,
                              void* d_out, int out_size, void* d_ws, size_t ws_size,
                              hipStream_t stream) {
    const float* feats  = (const float*)d_in[0];
    const float* y_s    = (const float*)d_in[1];
    const float* cov_in = (const float*)d_in[2];
    const float* Ave_in = (const float*)d_in[3];
    const float* Amount = (const float*)d_in[4];
    const int*   labels = (const int*)d_in[5];

    const int C = in_sizes[4];
    const int N = in_sizes[5];
    const int A = in_sizes[3] / C;

    float* out      = (float*)d_out;
    float* out_loss = out;
    float* out_cov  = out + 1;
    float* out_ave  = out_cov + (size_t)C * A * A;
    float* out_amt  = out_ave + (size_t)C * A;

    hipMemsetAsync(out_loss, 0, sizeof(float), stream);   // loss accumulator init

    const int nt = A / TM;                    // 4 tile positions per axis
    const int npairs = nt * (nt + 1) / 2;     // 10 upper-triangle tile pairs
    const int AZ = (C + npairs - 1) / npairs; // ave-rider z-slices
    dim3 grid(npairs, 1, LZ + AZ + C);        // riders at low z: dispatch first
    mega_kernel<<<grid, 256, 0, stream>>>(feats, cov_in, Ave_in, y_s, labels, Amount,
                                          out_cov, out_ave, out_amt, out_loss,
                                          N, C, A, 1.f / (float)N, AZ);
}